// Round 2
// baseline (1374.096 us; speedup 1.0000x reference)
//
#include <hip/hip_runtime.h>
#include <hip/hip_bf16.h>

// Problem constants (from reference): B=2, S=2048, D=1024, FFN=4096, V=32000, MAXSPAN=10
#define BB 2
#define SS 2048
#define DD 1024
#define FFN_ 4096
#define VV 32000
#define NTOK (BB * SS)   // 4096 tokens

typedef __attribute__((ext_vector_type(4))) float  f4;
typedef __attribute__((ext_vector_type(4))) float  f32x4;
typedef __attribute__((ext_vector_type(8))) short  bf16x8;
typedef __attribute__((ext_vector_type(8))) unsigned short u16x8;
typedef unsigned short ushort_t;

__device__ __forceinline__ ushort_t f2bf(float f) {
    unsigned int u = __float_as_uint(f);
    u += 0x7fffu + ((u >> 16) & 1u);   // round-to-nearest-even
    return (ushort_t)(u >> 16);
}

__device__ __forceinline__ float geluf(float x) {
    return 0.5f * x * (1.0f + erff(x * 0.70710678118654752f));
}

__device__ __forceinline__ void async16(const void* g, const void* l) {
    __builtin_amdgcn_global_load_lds(
        (const __attribute__((address_space(1))) void*)g,
        (__attribute__((address_space(3))) void*)l, 16, 0, 0);
}

// ---------------------------------------------------------------------------
// f32 -> bf16 conversion, 8 elems/thread, vectorized
// ---------------------------------------------------------------------------
__global__ __launch_bounds__(256) void cvt_bf16(const float* __restrict__ in,
                                                ushort_t* __restrict__ out, int n8) {
    int i = blockIdx.x * 256 + threadIdx.x;
    if (i >= n8) return;
    f4 a = ((const f4*)in)[2 * i];
    f4 b = ((const f4*)in)[2 * i + 1];
    u16x8 r;
#pragma unroll
    for (int j = 0; j < 4; ++j) { r[j] = f2bf(a[j]); r[4 + j] = f2bf(b[j]); }
    ((u16x8*)out)[i] = r;
}

// ---------------------------------------------------------------------------
// Span scatter: for masked tokens overwrite h row with [ctx_s | pos_emb | ctx_e]
// Spans are <= MAXSPAN long, so a local walk is cheap and exact.
// ---------------------------------------------------------------------------
__global__ __launch_bounds__(256) void span_scatter(const int* __restrict__ mask,
                                                    const ushort_t* __restrict__ hid_bf,
                                                    const float* __restrict__ pos_emb,
                                                    ushort_t* __restrict__ h) {
    int tok = blockIdx.x;                 // 0..NTOK-1
    if (mask[tok] != 1) return;
    int b = tok >> 11, s = tok & (SS - 1);
    const int* mrow = mask + b * SS;
    int st = s; while (st > 0 && mrow[st - 1] == 1) --st;
    int en = s; while (en < SS - 1 && mrow[en + 1] == 1) ++en;
    int cs = st - 1; if (cs < 0) cs = 0;
    int ce = en + 1; if (ce > SS - 1) ce = SS - 1;
    int pos = s - st; if (pos > 3 * 10 - 1) pos = 3 * 10 - 1;

    const ushort_t* hs = hid_bf + (size_t)(b * SS + cs) * DD;
    const ushort_t* he = hid_bf + (size_t)(b * SS + ce) * DD;
    const float* pe = pos_emb + (size_t)pos * DD;
    ushort_t* hr = h + (size_t)tok * (3 * DD);
    for (int c = threadIdx.x; c < DD; c += 256) {
        hr[c] = hs[c];
        hr[DD + c] = f2bf(pe[c]);
        hr[2 * DD + c] = he[c];
    }
}

// ---------------------------------------------------------------------------
// bf16 NT GEMM (m97 structure): C[M,N] = A[M,K] * W[N,K]^T  (+bias, gelu)
// 128x128 tile, BK=64, 256 threads = 4 waves (2x2), each wave 64x64 out,
// global_load_lds width 16, mfma_f32_16x16x32_bf16, f32 accumulate.
// All dims must divide: M%128==0, N%128==0, K%64==0 (true for every call here).
// ---------------------------------------------------------------------------
template <bool BIAS, bool GELU, bool OUTBF16>
__global__ __launch_bounds__(256) void gemm_bt(const ushort_t* __restrict__ A,
                                               const ushort_t* __restrict__ W,
                                               const float* __restrict__ bias,
                                               void* __restrict__ Cout,
                                               int M, int N, int K) {
    __shared__ ushort_t As[128 * 64];
    __shared__ ushort_t Bs[128 * 64];
    const int bm = blockIdx.y, bn = blockIdx.x;
    const int tid = threadIdx.x;
    const int lane = tid & 63, wave = tid >> 6;
    const int wr = wave >> 1, wc = wave & 1;

    f32x4 acc[4][4] = {};

    const size_t a0 = (size_t)bm * 128 * K;
    const size_t b0 = (size_t)bn * 128 * K;

    for (int k0 = 0; k0 < K; k0 += 64) {
#pragma unroll
        for (int i = 0; i < 4; ++i) {
            int li = i * 256 + tid;         // 0..1023 16B-chunks
            int r  = li >> 3;               // row in tile
            int kc = (li & 7) * 8;          // k offset (elems)
            async16(&A[a0 + (size_t)r * K + k0 + kc], &As[li * 8]);
            async16(&W[b0 + (size_t)r * K + k0 + kc], &Bs[li * 8]);
        }
        __syncthreads();
#pragma unroll
        for (int kk = 0; kk < 2; ++kk) {
            bf16x8 af[4], bfv[4];
#pragma unroll
            for (int m = 0; m < 4; ++m)
                af[m] = *(const bf16x8*)&As[(wr * 64 + m * 16 + (lane & 15)) * 64 + kk * 32 + (lane >> 4) * 8];
#pragma unroll
            for (int n = 0; n < 4; ++n)
                bfv[n] = *(const bf16x8*)&Bs[(wc * 64 + n * 16 + (lane & 15)) * 64 + kk * 32 + (lane >> 4) * 8];
#pragma unroll
            for (int m = 0; m < 4; ++m)
#pragma unroll
                for (int n = 0; n < 4; ++n)
                    acc[m][n] = __builtin_amdgcn_mfma_f32_16x16x32_bf16(af[m], bfv[n], acc[m][n], 0, 0, 0);
        }
        __syncthreads();
    }

    // Epilogue. D layout (verified m89/m91): col = lane&15, row = (lane>>4)*4 + j
    const int crow0 = bm * 128 + wr * 64;
    const int ccol0 = bn * 128 + wc * 64;
#pragma unroll
    for (int n = 0; n < 4; ++n) {
        int col = ccol0 + n * 16 + (lane & 15);
        float bv = 0.0f;
        if (BIAS) bv = bias[col];
#pragma unroll
        for (int m = 0; m < 4; ++m) {
#pragma unroll
            for (int j = 0; j < 4; ++j) {
                int row = crow0 + m * 16 + (lane >> 4) * 4 + j;
                float v = acc[m][n][j] + bv;
                if (GELU) v = geluf(v);
                if (OUTBF16)
                    ((ushort_t*)Cout)[(size_t)row * N + col] = f2bf(v);
                else
                    ((float*)Cout)[(size_t)row * N + col] = v;
            }
        }
    }
}

// ---------------------------------------------------------------------------
// Row LayerNorm (population var, eps=1e-5): f32 in -> bf16 out. 1 block/row.
// ---------------------------------------------------------------------------
template <int L>
__global__ __launch_bounds__(256) void ln_bf16(const float* __restrict__ x,
                                               const float* __restrict__ g,
                                               const float* __restrict__ be,
                                               ushort_t* __restrict__ out) {
    const int r = blockIdx.x;
    const f4* xr = (const f4*)(x + (size_t)r * L);
    constexpr int PT = L / 1024;            // float4s per thread
    f4 v[PT];
    float s = 0.f, s2 = 0.f;
#pragma unroll
    for (int i = 0; i < PT; ++i) {
        v[i] = xr[threadIdx.x + i * 256];
#pragma unroll
        for (int j = 0; j < 4; ++j) { s += v[i][j]; s2 += v[i][j] * v[i][j]; }
    }
#pragma unroll
    for (int o = 32; o; o >>= 1) { s += __shfl_xor(s, o); s2 += __shfl_xor(s2, o); }
    __shared__ float ss[4], ss2[4];
    int wave = threadIdx.x >> 6;
    if ((threadIdx.x & 63) == 0) { ss[wave] = s; ss2[wave] = s2; }
    __syncthreads();
    s  = ss[0] + ss[1] + ss[2] + ss[3];
    s2 = ss2[0] + ss2[1] + ss2[2] + ss2[3];
    const float mu   = s / L;
    const float var  = s2 / L - mu * mu;
    const float rstd = rsqrtf(var + 1e-5f);
#pragma unroll
    for (int i = 0; i < PT; ++i) {
        int c = (threadIdx.x + i * 256) * 4;
        ushort_t o4[4];
#pragma unroll
        for (int j = 0; j < 4; ++j)
            o4[j] = f2bf((v[i][j] - mu) * rstd * g[c + j] + be[c + j]);
        *(unsigned long long*)&out[(size_t)r * L + c] = *(unsigned long long*)o4;
    }
}

// ---------------------------------------------------------------------------
extern "C" void kernel_launch(void* const* d_in, const int* in_sizes, int n_in,
                              void* d_out, int out_size, void* d_ws, size_t ws_size,
                              hipStream_t stream) {
    const float* hidden   = (const float*)d_in[0];   // [B,S,D]
    const int*   mask     = (const int*)d_in[1];     // [B,S]
    const float* W_proj   = (const float*)d_in[2];   // [3D, D]
    const float* pos_emb  = (const float*)d_in[3];   // [30, D]
    const float* W1       = (const float*)d_in[4];   // [FFN, 3D]
    const float* b1       = (const float*)d_in[5];   // [FFN]
    const float* g1       = (const float*)d_in[6];
    const float* be1      = (const float*)d_in[7];
    const float* W2       = (const float*)d_in[8];   // [D, FFN]
    const float* g2       = (const float*)d_in[9];
    const float* be2      = (const float*)d_in[10];
    const float* W_cls    = (const float*)d_in[11];  // [V, D]
    const float* b_cls    = (const float*)d_in[12];  // [V]
    float* out = (float*)d_out;                      // [B,S,V]

    // workspace layout (~200 MB; t_raw aliased by W_cls bf16 after LN1)
    size_t off = 0;
    auto alloc = [&](size_t bytes) {
        void* p = (char*)d_ws + off;
        off += (bytes + 255) & ~(size_t)255;
        return p;
    };
    ushort_t* hid_bf  = (ushort_t*)alloc((size_t)NTOK * DD * 2);         // 8.4 MB
    ushort_t* Wp_bf   = (ushort_t*)alloc((size_t)3 * DD * DD * 2);       // 6.3 MB
    ushort_t* W1_bf   = (ushort_t*)alloc((size_t)FFN_ * 3 * DD * 2);     // 25.2 MB
    ushort_t* W2_bf   = (ushort_t*)alloc((size_t)DD * FFN_ * 2);         // 8.4 MB
    ushort_t* h_bf    = (ushort_t*)alloc((size_t)NTOK * 3 * DD * 2);     // 25.2 MB
    ushort_t* t_bf    = (ushort_t*)alloc((size_t)NTOK * FFN_ * 2);       // 33.6 MB
    float*    z_raw   = (float*)alloc((size_t)NTOK * DD * 4);            // 16.8 MB
    ushort_t* z_bf    = (ushort_t*)alloc((size_t)NTOK * DD * 2);         // 8.4 MB
    float*    t_raw   = (float*)alloc((size_t)NTOK * FFN_ * 4);          // 67.1 MB
    ushort_t* Wcls_bf = (ushort_t*)t_raw;  // alias: t_raw dead after LN1, Wcls (65.5MB) fits

    // 1) f32 -> bf16 conversions needed before GEMM1/2/3
    {
        int n8;
        n8 = NTOK * DD / 8;          cvt_bf16<<<(n8 + 255) / 256, 256, 0, stream>>>(hidden, hid_bf, n8);
        n8 = 3 * DD * DD / 8;        cvt_bf16<<<(n8 + 255) / 256, 256, 0, stream>>>(W_proj, Wp_bf, n8);
        n8 = FFN_ * 3 * DD / 8;      cvt_bf16<<<(n8 + 255) / 256, 256, 0, stream>>>(W1, W1_bf, n8);
        n8 = DD * FFN_ / 8;          cvt_bf16<<<(n8 + 255) / 256, 256, 0, stream>>>(W2, W2_bf, n8);
    }

    // 2) projector GEMM: h = hidden @ W_proj^T  -> bf16 [NTOK, 3D]
    gemm_bt<false, false, true><<<dim3(3 * DD / 128, NTOK / 128), 256, 0, stream>>>(
        hid_bf, Wp_bf, nullptr, h_bf, NTOK, 3 * DD, DD);

    // 3) scatter span embeddings over masked tokens
    span_scatter<<<NTOK, 256, 0, stream>>>(mask, hid_bf, pos_emb, h_bf);

    // 4) FFN-in: t_raw = gelu(h @ W1^T + b1)  -> f32 [NTOK, FFN]
    gemm_bt<true, true, false><<<dim3(FFN_ / 128, NTOK / 128), 256, 0, stream>>>(
        h_bf, W1_bf, b1, t_raw, NTOK, FFN_, 3 * DD);

    // 5) LN1 -> t_bf [NTOK, FFN]
    ln_bf16<FFN_><<<NTOK, 256, 0, stream>>>(t_raw, g1, be1, t_bf);

    // 6) convert W_cls (into the now-dead t_raw space)
    {
        int n8 = VV * DD / 8;
        cvt_bf16<<<(n8 + 255) / 256, 256, 0, stream>>>(W_cls, Wcls_bf, n8);
    }

    // 7) FFN-out: z_raw = gelu(t @ W2^T)  -> f32 [NTOK, D]
    gemm_bt<false, true, false><<<dim3(DD / 128, NTOK / 128), 256, 0, stream>>>(
        t_bf, W2_bf, nullptr, z_raw, NTOK, DD, FFN_);

    // 8) LN2 -> z_bf [NTOK, D]
    ln_bf16<DD><<<NTOK, 256, 0, stream>>>(z_raw, g2, be2, z_bf);

    // 9) classifier: out = z @ W_cls^T + b_cls  -> f32 [NTOK, V]
    gemm_bt<true, false, false><<<dim3(VV / 128, NTOK / 128), 256, 0, stream>>>(
        z_bf, Wcls_bf, b_cls, out, NTOK, VV, DD);
}